// Round 2
// baseline (1248.230 us; speedup 1.0000x reference)
//
#include <hip/hip_runtime.h>
#include <hip/hip_bf16.h>
#include <stdint.h>

#define M_TOK 8192
#define KDIM  4096
#define NDIM  11008
#define NBLK  256    // KDIM / 16

typedef __bf16 bf16x8 __attribute__((ext_vector_type(8)));
typedef float  f32x4  __attribute__((ext_vector_type(4)));
typedef unsigned short ushort8 __attribute__((ext_vector_type(8)));

__device__ __forceinline__ unsigned short f2b(float f) {
    union { float f; unsigned int i; } v; v.f = f;
    unsigned int u = v.i;
    unsigned int r = (u + 0x7fffu + ((u >> 16) & 1u)) >> 16;
    return (unsigned short)r;
}

__device__ __forceinline__ void gl_lds16(const void* g, void* l) {
    __builtin_amdgcn_global_load_lds(
        (const __attribute__((address_space(1))) unsigned int*)g,
        (__attribute__((address_space(3))) unsigned int*)l, 16, 0, 0);
}

// ---------------------------------------------------------------------------
// Kernel 1: xt[m, b*16+j] = sum_i x[m, perm[b*16+i]] * R[b, i, j]
// x, R are FLOAT32 (harness promotes fp16 inputs). xt is bf16 (internal).
// grid: (NBLK, M/256), block: 256
// ---------------------------------------------------------------------------
__global__ __launch_bounds__(256) void rotate_kernel(
    const float* __restrict__ x, const float* __restrict__ R,
    const int* __restrict__ perm, unsigned short* __restrict__ xt)
{
    __shared__ float Rs[16][17];
    __shared__ int   ps[16];
    const int b = blockIdx.x;
    const int t = threadIdx.x;
    Rs[t >> 4][t & 15] = R[b * 256 + t];
    if (t < 16) ps[t] = perm[b * 16 + t];
    __syncthreads();

    const int m = blockIdx.y * 256 + t;
    const float* xrow = x + (size_t)m * KDIM;
    float xv[16];
#pragma unroll
    for (int i = 0; i < 16; ++i) xv[i] = xrow[ps[i]];

    unsigned short o[16] __attribute__((aligned(16)));
#pragma unroll
    for (int j = 0; j < 16; ++j) {
        float acc = 0.f;
#pragma unroll
        for (int i = 0; i < 16; ++i) acc += xv[i] * Rs[i][j];
        o[j] = f2b(acc);
    }
    unsigned short* dst = xt + (size_t)m * KDIM + b * 16;
    *(ushort8*)dst       = *(ushort8*)o;
    *(ushort8*)(dst + 8) = *(ushort8*)(o + 8);
}

// ---------------------------------------------------------------------------
// Kernel 2: Wd[n,k] = (float(q[n,k]) - zeros[n]) * scales[n]  -> bf16
// q int32 (values 0..15), scales/zeros FLOAT32. 8 elements / thread.
// ---------------------------------------------------------------------------
__global__ __launch_bounds__(256) void dequant_kernel(
    const int* __restrict__ q, const float* __restrict__ scales,
    const float* __restrict__ zeros, unsigned short* __restrict__ w)
{
    const int idx8 = blockIdx.x * 256 + threadIdx.x;
    const size_t base = (size_t)idx8 * 8;
    const int n = (int)(base >> 12);   // /KDIM
    const float s = scales[n];
    const float z = zeros[n];
    const int4* qp = (const int4*)(q + base);
    const int4 q0 = qp[0], q1 = qp[1];
    unsigned short o[8] __attribute__((aligned(16)));
    o[0] = f2b(((float)q0.x - z) * s);
    o[1] = f2b(((float)q0.y - z) * s);
    o[2] = f2b(((float)q0.z - z) * s);
    o[3] = f2b(((float)q0.w - z) * s);
    o[4] = f2b(((float)q1.x - z) * s);
    o[5] = f2b(((float)q1.y - z) * s);
    o[6] = f2b(((float)q1.z - z) * s);
    o[7] = f2b(((float)q1.w - z) * s);
    *(ushort8*)(w + base) = *(ushort8*)o;
}

// ---------------------------------------------------------------------------
// Kernel 3: C[m,n] = sum_k A[m,k] * B[n,k]   (A: xt MxK, B: Wd NxK, bf16)
// C is FLOAT32. m97 structure: 128x128 tile, BK=32, 4 waves (2x2),
// 4x4 16x16x32 frags/wave, global_load_lds width-16 into linear LDS.
// ---------------------------------------------------------------------------
__global__ __launch_bounds__(256, 3) void gemm_bt(
    const unsigned short* __restrict__ A, const unsigned short* __restrict__ B,
    float* __restrict__ C)
{
    __shared__ unsigned short As[128 * 32];
    __shared__ unsigned short Bs[128 * 32];

    const int tid  = threadIdx.x;
    const int wave = tid >> 6;
    const int lane = tid & 63;

    // XCD-aware swizzle: 5504 workgroups = 8 * 688 (bijective)
    const int wg  = blockIdx.x;
    const int swz = (wg & 7) * 688 + (wg >> 3);
    const int tm  = swz / 86;
    const int tn  = swz % 86;

    // staging: thread t loads 16B chunk (row = t>>2, col8 = (t&3)*8),
    // rounds at row and row+64. LDS dest linear by tid (wave-uniform base).
    const unsigned short* aSrc = A + (size_t)(tm * 128 + (tid >> 2)) * KDIM + (tid & 3) * 8;
    const unsigned short* bSrc = B + (size_t)(tn * 128 + (tid >> 2)) * KDIM + (tid & 3) * 8;

    char* asBase = (char*)As + wave * 1024;
    char* bsBase = (char*)Bs + wave * 1024;

    f32x4 acc[4][4] = {};

    const int wr = wave >> 1, wc = wave & 1;
    const int rr = lane & 15;
    const int kq = (lane >> 4) * 8;

    for (int k0 = 0; k0 < KDIM; k0 += 32) {
        gl_lds16(aSrc + k0,                      asBase);
        gl_lds16(aSrc + (size_t)64 * KDIM + k0,  asBase + 4096);
        gl_lds16(bSrc + k0,                      bsBase);
        gl_lds16(bSrc + (size_t)64 * KDIM + k0,  bsBase + 4096);
        __syncthreads();

        bf16x8 af[4], bg[4];
#pragma unroll
        for (int i = 0; i < 4; ++i) {
            af[i] = *(const bf16x8*)&As[(wr * 64 + i * 16 + rr) * 32 + kq];
            bg[i] = *(const bf16x8*)&Bs[(wc * 64 + i * 16 + rr) * 32 + kq];
        }
#pragma unroll
        for (int i = 0; i < 4; ++i)
#pragma unroll
            for (int j = 0; j < 4; ++j)
                acc[i][j] = __builtin_amdgcn_mfma_f32_16x16x32_bf16(af[i], bg[j], acc[i][j], 0, 0, 0);
        __syncthreads();
    }

    // epilogue: C/D layout col = lane&15, row = (lane>>4)*4 + reg. f32 stores.
#pragma unroll
    for (int i = 0; i < 4; ++i) {
        const int r0 = tm * 128 + wr * 64 + i * 16 + (lane >> 4) * 4;
#pragma unroll
        for (int j = 0; j < 4; ++j) {
            const int c0 = tn * 128 + wc * 64 + j * 16 + rr;
#pragma unroll
            for (int r = 0; r < 4; ++r)
                C[(size_t)(r0 + r) * NDIM + c0] = acc[i][j][r];
        }
    }
}

extern "C" void kernel_launch(void* const* d_in, const int* in_sizes, int n_in,
                              void* d_out, int out_size, void* d_ws, size_t ws_size,
                              hipStream_t stream) {
    const float* x      = (const float*)d_in[0];
    const float* R      = (const float*)d_in[1];
    const float* scales = (const float*)d_in[2];
    const float* zeros  = (const float*)d_in[3];
    const int*   perm   = (const int*)d_in[4];
    const int*   qw     = (const int*)d_in[5];
    float*       out    = (float*)d_out;

    unsigned short* xt = (unsigned short*)d_ws;          // 8192*4096 bf16 = 64 MiB
    unsigned short* wd = xt + (size_t)M_TOK * KDIM;      // 11008*4096 bf16 = 86 MiB

    rotate_kernel<<<dim3(NBLK, M_TOK / 256), 256, 0, stream>>>(x, R, perm, xt);
    dequant_kernel<<<dim3((int)(((size_t)NDIM * KDIM) / 8 / 256)), 256, 0, stream>>>(qw, scales, zeros, wd);
    gemm_bt<<<dim3((M_TOK / 128) * (NDIM / 128)), 256, 0, stream>>>(xt, wd, out);
}

// Round 3
// 1189.457 us; speedup vs baseline: 1.0494x; 1.0494x over previous
//
#include <hip/hip_runtime.h>
#include <hip/hip_bf16.h>
#include <stdint.h>

#define M_TOK 8192
#define KDIM  4096
#define NDIM  11008
#define NBLK  256    // KDIM / 16

typedef __bf16 bf16x8 __attribute__((ext_vector_type(8)));
typedef float  f32x4  __attribute__((ext_vector_type(4)));
typedef unsigned short ushort8 __attribute__((ext_vector_type(8)));

__device__ __forceinline__ unsigned short f2b(float f) {
    union { float f; unsigned int i; } v; v.f = f;
    unsigned int u = v.i;
    unsigned int r = (u + 0x7fffu + ((u >> 16) & 1u)) >> 16;
    return (unsigned short)r;
}

__device__ __forceinline__ void gl_lds16(const void* g, void* l) {
    __builtin_amdgcn_global_load_lds(
        (const __attribute__((address_space(1))) unsigned int*)g,
        (__attribute__((address_space(3))) unsigned int*)l, 16, 0, 0);
}

// ---------------------------------------------------------------------------
// Kernel 1: xt[m, b*16+j] = sum_i x[m, perm[b*16+i]] * R[b, i, j]
// x, R are FLOAT32 (harness promotes fp16 inputs). xt is bf16 (internal).
// ---------------------------------------------------------------------------
__global__ __launch_bounds__(256) void rotate_kernel(
    const float* __restrict__ x, const float* __restrict__ R,
    const int* __restrict__ perm, unsigned short* __restrict__ xt)
{
    __shared__ float Rs[16][17];
    __shared__ int   ps[16];
    const int b = blockIdx.x;
    const int t = threadIdx.x;
    Rs[t >> 4][t & 15] = R[b * 256 + t];
    if (t < 16) ps[t] = perm[b * 16 + t];
    __syncthreads();

    const int m = blockIdx.y * 256 + t;
    const float* xrow = x + (size_t)m * KDIM;
    float xv[16];
#pragma unroll
    for (int i = 0; i < 16; ++i) xv[i] = xrow[ps[i]];

    unsigned short o[16] __attribute__((aligned(16)));
#pragma unroll
    for (int j = 0; j < 16; ++j) {
        float acc = 0.f;
#pragma unroll
        for (int i = 0; i < 16; ++i) acc += xv[i] * Rs[i][j];
        o[j] = f2b(acc);
    }
    unsigned short* dst = xt + (size_t)m * KDIM + b * 16;
    *(ushort8*)dst       = *(ushort8*)o;
    *(ushort8*)(dst + 8) = *(ushort8*)(o + 8);
}

// ---------------------------------------------------------------------------
// Kernel 2: Wd[n,k] = (float(q[n,k]) - zeros[n]) * scales[n]  -> bf16
// ---------------------------------------------------------------------------
__global__ __launch_bounds__(256) void dequant_kernel(
    const int* __restrict__ q, const float* __restrict__ scales,
    const float* __restrict__ zeros, unsigned short* __restrict__ w)
{
    const int idx8 = blockIdx.x * 256 + threadIdx.x;
    const size_t base = (size_t)idx8 * 8;
    const int n = (int)(base >> 12);   // /KDIM
    const float s = scales[n];
    const float z = zeros[n];
    const int4* qp = (const int4*)(q + base);
    const int4 q0 = qp[0], q1 = qp[1];
    unsigned short o[8] __attribute__((aligned(16)));
    o[0] = f2b(((float)q0.x - z) * s);
    o[1] = f2b(((float)q0.y - z) * s);
    o[2] = f2b(((float)q0.z - z) * s);
    o[3] = f2b(((float)q0.w - z) * s);
    o[4] = f2b(((float)q1.x - z) * s);
    o[5] = f2b(((float)q1.y - z) * s);
    o[6] = f2b(((float)q1.z - z) * s);
    o[7] = f2b(((float)q1.w - z) * s);
    *(ushort8*)(w + base) = *(ushort8*)o;
}

// ---------------------------------------------------------------------------
// Kernel 3: C[m,n] = sum_k A[m,k] * B[n,k]   (A: xt MxK, B: Wd NxK, bf16)
// C FLOAT32. m97 structure (unchanged from round 2 except block ordering):
// tn-MAJOR enumeration (tm fastest) so a 64-block column shares one B panel
// (L2-resident per XCD) and A panels cycle with 64 MB reuse distance (L3).
// ---------------------------------------------------------------------------
__global__ __launch_bounds__(256, 3) void gemm_bt(
    const unsigned short* __restrict__ A, const unsigned short* __restrict__ B,
    float* __restrict__ C)
{
    __shared__ unsigned short As[128 * 32];
    __shared__ unsigned short Bs[128 * 32];

    const int tid  = threadIdx.x;
    const int wave = tid >> 6;
    const int lane = tid & 63;

    // XCD-aware swizzle: 5504 workgroups = 8 * 688 (bijective)
    const int wg  = blockIdx.x;
    const int swz = (wg & 7) * 688 + (wg >> 3);
    // tn-major: consecutive swz walk tm within a fixed tn column
    const int tm  = swz & 63;    // M/128 = 64
    const int tn  = swz >> 6;    // N/128 = 86

    const unsigned short* aSrc = A + (size_t)(tm * 128 + (tid >> 2)) * KDIM + (tid & 3) * 8;
    const unsigned short* bSrc = B + (size_t)(tn * 128 + (tid >> 2)) * KDIM + (tid & 3) * 8;

    char* asBase = (char*)As + wave * 1024;
    char* bsBase = (char*)Bs + wave * 1024;

    f32x4 acc[4][4] = {};

    const int wr = wave >> 1, wc = wave & 1;
    const int rr = lane & 15;
    const int kq = (lane >> 4) * 8;

    for (int k0 = 0; k0 < KDIM; k0 += 32) {
        gl_lds16(aSrc + k0,                      asBase);
        gl_lds16(aSrc + (size_t)64 * KDIM + k0,  asBase + 4096);
        gl_lds16(bSrc + k0,                      bsBase);
        gl_lds16(bSrc + (size_t)64 * KDIM + k0,  bsBase + 4096);
        __syncthreads();

        bf16x8 af[4], bg[4];
#pragma unroll
        for (int i = 0; i < 4; ++i) {
            af[i] = *(const bf16x8*)&As[(wr * 64 + i * 16 + rr) * 32 + kq];
            bg[i] = *(const bf16x8*)&Bs[(wc * 64 + i * 16 + rr) * 32 + kq];
        }
#pragma unroll
        for (int i = 0; i < 4; ++i)
#pragma unroll
            for (int j = 0; j < 4; ++j)
                acc[i][j] = __builtin_amdgcn_mfma_f32_16x16x32_bf16(af[i], bg[j], acc[i][j], 0, 0, 0);
        __syncthreads();
    }

    // epilogue: C/D layout col = lane&15, row = (lane>>4)*4 + reg. f32 stores.
#pragma unroll
    for (int i = 0; i < 4; ++i) {
        const int r0 = tm * 128 + wr * 64 + i * 16 + (lane >> 4) * 4;
#pragma unroll
        for (int j = 0; j < 4; ++j) {
            const int c0 = tn * 128 + wc * 64 + j * 16 + rr;
#pragma unroll
            for (int r = 0; r < 4; ++r)
                C[(size_t)(r0 + r) * NDIM + c0] = acc[i][j][r];
        }
    }
}

extern "C" void kernel_launch(void* const* d_in, const int* in_sizes, int n_in,
                              void* d_out, int out_size, void* d_ws, size_t ws_size,
                              hipStream_t stream) {
    const float* x      = (const float*)d_in[0];
    const float* R      = (const float*)d_in[1];
    const float* scales = (const float*)d_in[2];
    const float* zeros  = (const float*)d_in[3];
    const int*   perm   = (const int*)d_in[4];
    const int*   qw     = (const int*)d_in[5];
    float*       out    = (float*)d_out;

    unsigned short* xt = (unsigned short*)d_ws;          // 64 MiB
    unsigned short* wd = xt + (size_t)M_TOK * KDIM;      // 86 MiB

    rotate_kernel<<<dim3(NBLK, M_TOK / 256), 256, 0, stream>>>(x, R, perm, xt);
    dequant_kernel<<<dim3((int)(((size_t)NDIM * KDIM) / 8 / 256)), 256, 0, stream>>>(qw, scales, zeros, wd);
    gemm_bt<<<dim3((M_TOK / 128) * (NDIM / 128)), 256, 0, stream>>>(xt, wd, out);
}

// Round 4
// 851.663 us; speedup vs baseline: 1.4656x; 1.3966x over previous
//
#include <hip/hip_runtime.h>
#include <hip/hip_bf16.h>
#include <stdint.h>

#define M_TOK 8192
#define KDIM  4096
#define NDIM  11008
#define NBLK  256      // KDIM / 16
#define K2    8192     // KDIM * 2 bytes (row stride of xt/wd)

typedef __bf16 bf16x8 __attribute__((ext_vector_type(8)));
typedef float  f32x4  __attribute__((ext_vector_type(4)));
typedef unsigned short ushort8 __attribute__((ext_vector_type(8)));

__device__ __forceinline__ unsigned short f2b(float f) {
    union { float f; unsigned int i; } v; v.f = f;
    unsigned int u = v.i;
    unsigned int r = (u + 0x7fffu + ((u >> 16) & 1u)) >> 16;
    return (unsigned short)r;
}

__device__ __forceinline__ void gl_lds16(const void* g, void* l) {
    __builtin_amdgcn_global_load_lds(
        (const __attribute__((address_space(1))) unsigned int*)g,
        (__attribute__((address_space(3))) unsigned int*)l, 16, 0, 0);
}

// ---------------------------------------------------------------------------
// Kernel 1: xt[m, b*16+j] = sum_i x[m, perm[b*16+i]] * R[b, i, j]  (f32 -> bf16)
// ---------------------------------------------------------------------------
__global__ __launch_bounds__(256) void rotate_kernel(
    const float* __restrict__ x, const float* __restrict__ R,
    const int* __restrict__ perm, unsigned short* __restrict__ xt)
{
    __shared__ float Rs[16][17];
    __shared__ int   ps[16];
    const int b = blockIdx.x;
    const int t = threadIdx.x;
    Rs[t >> 4][t & 15] = R[b * 256 + t];
    if (t < 16) ps[t] = perm[b * 16 + t];
    __syncthreads();

    const int m = blockIdx.y * 256 + t;
    const float* xrow = x + (size_t)m * KDIM;
    float xv[16];
#pragma unroll
    for (int i = 0; i < 16; ++i) xv[i] = xrow[ps[i]];

    unsigned short o[16] __attribute__((aligned(16)));
#pragma unroll
    for (int j = 0; j < 16; ++j) {
        float acc = 0.f;
#pragma unroll
        for (int i = 0; i < 16; ++i) acc += xv[i] * Rs[i][j];
        o[j] = f2b(acc);
    }
    unsigned short* dst = xt + (size_t)m * KDIM + b * 16;
    *(ushort8*)dst       = *(ushort8*)o;
    *(ushort8*)(dst + 8) = *(ushort8*)(o + 8);
}

// ---------------------------------------------------------------------------
// Kernel 2: Wd[n,k] = (float(q[n,k]) - zeros[n]) * scales[n] -> bf16
// ---------------------------------------------------------------------------
__global__ __launch_bounds__(256) void dequant_kernel(
    const int* __restrict__ q, const float* __restrict__ scales,
    const float* __restrict__ zeros, unsigned short* __restrict__ w)
{
    const int idx8 = blockIdx.x * 256 + threadIdx.x;
    const size_t base = (size_t)idx8 * 8;
    const int n = (int)(base >> 12);
    const float s = scales[n];
    const float z = zeros[n];
    const int4* qp = (const int4*)(q + base);
    const int4 q0 = qp[0], q1 = qp[1];
    unsigned short o[8] __attribute__((aligned(16)));
    o[0] = f2b(((float)q0.x - z) * s);
    o[1] = f2b(((float)q0.y - z) * s);
    o[2] = f2b(((float)q0.z - z) * s);
    o[3] = f2b(((float)q0.w - z) * s);
    o[4] = f2b(((float)q1.x - z) * s);
    o[5] = f2b(((float)q1.y - z) * s);
    o[6] = f2b(((float)q1.z - z) * s);
    o[7] = f2b(((float)q1.w - z) * s);
    *(ushort8*)(w + base) = *(ushort8*)o;
}

// ---------------------------------------------------------------------------
// Kernel 3: 256x256 8-phase GEMM (m201-style), C[m,n] = sum_k A[m,k]*B[n,k]
// A: xt (M x K bf16), B: wd (N x K bf16), C: f32.
// 512 threads = 8 waves (2M x 4N); BK=64; LDS 128 KiB (2 buffers).
// T2 swizzle: LDS colByte ^= ((row&7)<<4); staging pre-swizzles the GLOBAL
// source (global_load_lds writes linearly). Counted vmcnt(4) at tile ends.
// ---------------------------------------------------------------------------
#define ABASE(bb) ((bb)*65536)
#define BBASE(bb) ((bb)*65536 + 32768)

#define BAR() do { asm volatile("" ::: "memory"); __builtin_amdgcn_s_barrier(); \
                   asm volatile("" ::: "memory"); } while (0)
#define WAITV(n) asm volatile("s_waitcnt vmcnt(" #n ")" ::: "memory")
#define PRIO1 __builtin_amdgcn_s_setprio(1)
#define PRIO0 __builtin_amdgcn_s_setprio(0)

// stage half-tiles: A halves (4 loads) / B half0 (2) / B half1 (2)
#define STAGE_A(bb, kB) do { \
    gl_lds16(aStageBase + (size_t)(  0)*K2 + (kB), lds + ABASE(bb) +     0 + wOff); \
    gl_lds16(aStageBase + (size_t)( 64)*K2 + (kB), lds + ABASE(bb) +  8192 + wOff); \
    gl_lds16(aStageBase + (size_t)(128)*K2 + (kB), lds + ABASE(bb) + 16384 + wOff); \
    gl_lds16(aStageBase + (size_t)(192)*K2 + (kB), lds + ABASE(bb) + 24576 + wOff); \
} while (0)
#define STAGE_B0(bb, kB) do { \
    gl_lds16(bStageBase + (size_t)(  0)*K2 + (kB), lds + BBASE(bb) +     0 + wOff); \
    gl_lds16(bStageBase + (size_t)( 64)*K2 + (kB), lds + BBASE(bb) +  8192 + wOff); \
} while (0)
#define STAGE_B1(bb, kB) do { \
    gl_lds16(bStageBase + (size_t)(128)*K2 + (kB), lds + BBASE(bb) + 16384 + wOff); \
    gl_lds16(bStageBase + (size_t)(192)*K2 + (kB), lds + BBASE(bb) + 24576 + wOff); \
} while (0)

#define PH_READ_A(bb, mh) do { \
    _Pragma("unroll") \
    for (int mf = 0; mf < 4; ++mf) { \
        aF[mf][0] = *(const bf16x8*)(lds + ABASE(bb) + aRdBase + ((mh)*64 + mf*16)*128 + cs0); \
        aF[mf][1] = *(const bf16x8*)(lds + ABASE(bb) + aRdBase + ((mh)*64 + mf*16)*128 + cs1); \
    } \
} while (0)
#define PH_READ_B(bb, nh) do { \
    _Pragma("unroll") \
    for (int nf = 0; nf < 2; ++nf) { \
        bF[nh][nf][0] = *(const bf16x8*)(lds + BBASE(bb) + bRdBase + ((nh)*32 + nf*16)*128 + cs0); \
        bF[nh][nf][1] = *(const bf16x8*)(lds + BBASE(bb) + bRdBase + ((nh)*32 + nf*16)*128 + cs1); \
    } \
} while (0)

#define MFMA_Q(mh, nh) do { \
    _Pragma("unroll") \
    for (int mf = 0; mf < 4; ++mf) \
    _Pragma("unroll") \
    for (int nf = 0; nf < 2; ++nf) { \
        acc[(mh)*4+mf][(nh)*2+nf] = __builtin_amdgcn_mfma_f32_16x16x32_bf16( \
            aF[mf][0], bF[nh][nf][0], acc[(mh)*4+mf][(nh)*2+nf], 0, 0, 0); \
        acc[(mh)*4+mf][(nh)*2+nf] = __builtin_amdgcn_mfma_f32_16x16x32_bf16( \
            aF[mf][1], bF[nh][nf][1], acc[(mh)*4+mf][(nh)*2+nf], 0, 0, 0); \
    } \
} while (0)

// MODE: 0 steady, 1 tail (stage B of t+1 only, drain vmcnt), 2 last (nothing)
#define TILE(bb, kB, MODE) do { \
    PH_READ_A(bb, 0); PH_READ_B(bb, 0); \
    if ((MODE) <= 1) STAGE_B0((bb)^1, (kB) + 128); \
    BAR(); PRIO1; MFMA_Q(0, 0); PRIO0; BAR(); \
    PH_READ_B(bb, 1); \
    if ((MODE) <= 1) STAGE_B1((bb)^1, (kB) + 128); \
    BAR(); PRIO1; MFMA_Q(0, 1); PRIO0; BAR(); \
    PH_READ_A(bb, 1); \
    BAR(); PRIO1; MFMA_Q(1, 0); PRIO0; BAR(); \
    if ((MODE) == 0) STAGE_A(bb, (kB) + 256); \
    PRIO1; MFMA_Q(1, 1); PRIO0; \
    if ((MODE) == 0) WAITV(4); \
    if ((MODE) == 1) WAITV(0); \
    BAR(); \
} while (0)

__global__ __launch_bounds__(512, 2) void gemm_bt256(
    const unsigned short* __restrict__ Aq, const unsigned short* __restrict__ Bq,
    float* __restrict__ C)
{
    __shared__ char lds[131072];

    const int tid  = threadIdx.x;
    const int wave = tid >> 6;
    const int lane = tid & 63;
    const int wr   = wave >> 2;      // 0..1 (M)
    const int wc   = wave & 3;       // 0..3 (N)

    // XCD-aware bijective swizzle: 1376 wg = 8 * 172; tn-major (tm fastest)
    const int wg  = blockIdx.x;
    const int swz = (wg & 7) * 172 + (wg >> 3);
    const int tm  = swz & 31;        // M/256 = 32
    const int tn  = swz >> 5;        // N/256 = 43

    // ---- staging addresses (pre-swizzled global source, linear LDS dest) ----
    const int gRow    = wave * 8 + (lane >> 3);                    // 0..63 per round
    const int gColSwz = (((lane & 7) ^ ((lane >> 3) & 7)) << 4);   // involution
    const char* aStageBase = (const char*)Aq + (size_t)(tm * 256 + gRow) * K2 + gColSwz;
    const char* bStageBase = (const char*)Bq + (size_t)(tn * 256 + gRow) * K2 + gColSwz;
    const int wOff = wave * 1024;

    // ---- ds_read addressing (swizzled) ----
    const int laneRow128 = (lane & 15) * 128;
    const int lx  = (lane & 7) << 4;
    const int cs0 = (((lane >> 4) * 16)      ) ^ lx;   // k-cols 0..31
    const int cs1 = (((lane >> 4) * 16) + 64 ) ^ lx;   // k-cols 32..63
    const int aRdBase = wr * 16384 + laneRow128;
    const int bRdBase = (wc >> 1) * 16384 + (wc & 1) * 8192 + laneRow128;

    f32x4  acc[8][4] = {};
    bf16x8 aF[4][2];
    bf16x8 bF[2][2][2];

    // ---- prologue: tile0 (A,B) + tile1 (A) ----
    STAGE_A(0, 0);
    STAGE_B0(0, 0); STAGE_B1(0, 0);
    STAGE_A(1, 128);
    WAITV(4);
    BAR();

    int kB = 0;
#pragma unroll 1
    for (int t = 0; t < 61; t += 2) {   // tiles 0..61 steady
        TILE(0, kB, 0);
        TILE(1, kB + 128, 0);
        kB += 256;
    }
    TILE(0, 62 * 128, 1);               // tile 62: stage B(63), drain
    TILE(1, 63 * 128, 2);               // tile 63: compute only

    // ---- epilogue: C/D layout col = lane&15, row = (lane>>4)*4 + reg ----
    const int row0 = tm * 256 + wr * 128 + (lane >> 4) * 4;
    const int col0 = tn * 256 + wc * 64 + (lane & 15);
#pragma unroll
    for (int mi = 0; mi < 8; ++mi) {
#pragma unroll
        for (int ni = 0; ni < 4; ++ni) {
            const f32x4 v = acc[mi][ni];
            const size_t r = (size_t)(row0 + mi * 16);
            const int    c = col0 + ni * 16;
            C[(r + 0) * NDIM + c] = v[0];
            C[(r + 1) * NDIM + c] = v[1];
            C[(r + 2) * NDIM + c] = v[2];
            C[(r + 3) * NDIM + c] = v[3];
        }
    }
}

extern "C" void kernel_launch(void* const* d_in, const int* in_sizes, int n_in,
                              void* d_out, int out_size, void* d_ws, size_t ws_size,
                              hipStream_t stream) {
    const float* x      = (const float*)d_in[0];
    const float* R      = (const float*)d_in[1];
    const float* scales = (const float*)d_in[2];
    const float* zeros  = (const float*)d_in[3];
    const int*   perm   = (const int*)d_in[4];
    const int*   qw     = (const int*)d_in[5];
    float*       out    = (float*)d_out;

    unsigned short* xt = (unsigned short*)d_ws;          // 64 MiB
    unsigned short* wd = xt + (size_t)M_TOK * KDIM;      // 86 MiB

    rotate_kernel<<<dim3(NBLK, M_TOK / 256), 256, 0, stream>>>(x, R, perm, xt);
    dequant_kernel<<<dim3((int)(((size_t)NDIM * KDIM) / 8 / 256)), 256, 0, stream>>>(qw, scales, zeros, wd);
    gemm_bt256<<<dim3((M_TOK / 256) * (NDIM / 256)), 512, 0, stream>>>(xt, wd, out);
}